// Round 7
// baseline (396.321 us; speedup 1.0000x reference)
//
#include <hip/hip_runtime.h>

typedef unsigned short u16;
typedef unsigned int u32;
typedef unsigned long long u64;
typedef __bf16 bf16x8 __attribute__((ext_vector_type(8)));
typedef float f32x4 __attribute__((ext_vector_type(4)));

#define B_  4
#define T_  2048
#define C_  1024
#define NH_ 16
#define D_  64
#define M_  (B_*T_)          // 8192
#define N_QKV (3*C_)         // 3072

#define ATTN_BLOCKS 1024     // one (bh, 128-row qtile) per block, 4 blocks/CU

// raw barrier + static waitcnt (no vmcnt(0) drain -- keeps prefetch in flight)
#define BARRIER()  __asm__ __volatile__("s_barrier" ::: "memory")
#define WAIT_VM4() __asm__ __volatile__("s_waitcnt vmcnt(4)" ::: "memory")
#define WAIT_VM8() __asm__ __volatile__("s_waitcnt vmcnt(8)" ::: "memory")
#define WAIT_VM0() __asm__ __volatile__("s_waitcnt vmcnt(0)" ::: "memory")
#define LGKM0()    __asm__ __volatile__("s_waitcnt lgkmcnt(0)" ::: "memory")

// async global->LDS, 16B per lane. LDS dest = wave-uniform base + lane*16
__device__ __forceinline__ void async_copy16(void* lds, const void* gptr) {
  __builtin_amdgcn_global_load_lds(
      (const __attribute__((address_space(1))) u32*)gptr,
      (__attribute__((address_space(3))) u32*)(u32)(uintptr_t)lds,
      16, 0, 0);
}

// RNE float -> bf16 bits
__device__ __forceinline__ u16 f2bf(float f) {
  union { float f; unsigned u; } c; c.f = f;
  unsigned u = c.u;
  unsigned r = (u + 0x7fffu + ((u >> 16) & 1u)) >> 16;
  return (u16)r;
}

// ---------------- elementwise fp32 -> bf16 ----------------
__global__ __launch_bounds__(256) void conv_bf16(const float* __restrict__ in,
                                                 u16* __restrict__ out, int n) {
  int i = (blockIdx.x * 256 + threadIdx.x) * 4;
  if (i < n) {
    float4 f = *reinterpret_cast<const float4*>(in + i);
    u16 o[4] = { f2bf(f.x), f2bf(f.y), f2bf(f.z), f2bf(f.w) };
    *reinterpret_cast<uint2*>(out + i) = *reinterpret_cast<uint2*>(o);
  }
}

// ---------------- transpose fp32 [K][N] -> bf16 [N][K] ----------------
__global__ __launch_bounds__(256) void transpose_bf16(const float* __restrict__ in,
                                                      u16* __restrict__ out,
                                                      int K, int N) {
  __shared__ float tile[32][33];
  int bi = blockIdx.y;
  int bj = blockIdx.x;
  int tx = threadIdx.x & 31;
  int ty = threadIdx.x >> 5;
#pragma unroll
  for (int i = 0; i < 4; ++i) {
    int row = ty + i * 8;
    tile[row][tx] = in[(bi * 32 + row) * N + bj * 32 + tx];
  }
  __syncthreads();
#pragma unroll
  for (int i = 0; i < 4; ++i) {
    int row = ty + i * 8;
    out[(bj * 32 + row) * K + bi * 32 + tx] = f2bf(tile[tx][row]);
  }
}

// ---------------- QKV GEMM: 128x128, BK=64, prefetched 2-phase ----------------
// Q/K blocks (bn<16, uniform per block) compute the TRANSPOSED C fragment by
// swapping the MFMA operands -- lane holds 4 consecutive channels d in its
// r-quad -> one uint2 store; bias/bQ/bK become aligned float4 loads.
// (verified R6: qkv ~104 -> ~78 us)
__global__ __launch_bounds__(256, 2) void gemm_qkv(const u16* __restrict__ A,
                                                   const u16* __restrict__ Bt,
                                                   const float* __restrict__ b_attn,
                                                   const float* __restrict__ bQ,
                                                   const float* __restrict__ bK,
                                                   u16* __restrict__ qo,
                                                   u16* __restrict__ ko,
                                                   u16* __restrict__ vo) {
  const int K = C_;
  // bijective XCD swizzle: 1536 = 8 x 192; bm-major inside a chunk
  int bid = blockIdx.x;
  int wg = (bid & 7) * 192 + (bid >> 3);
  int bm = wg / 24, bn = wg % 24;
  const bool qk = (bn < 16);          // Q or K block (uniform)

  int tid = threadIdx.x;
  int wid = tid >> 6, lane = tid & 63;
  int lm = lane & 15, lq = lane >> 4;
  int wm = (wid >> 1) * 64, wn = (wid & 1) * 64;

  __shared__ u16 As[2][128 * 64];
  __shared__ u16 Bs[2][128 * 64];

  f32x4 acc[4][4];
#pragma unroll
  for (int i = 0; i < 4; ++i)
#pragma unroll
    for (int j = 0; j < 4; ++j) acc[i][j] = (f32x4){0.f, 0.f, 0.f, 0.f};

  const u16* Ab = A + (size_t)(bm * 128) * K;
  const u16* Bb = Bt + (size_t)(bn * 128) * K;
  int srow = lane >> 3;                  // row within 8-row chunk
  int sgc  = ((lane & 7) ^ srow) * 8;    // pre-swizzled global u16 col offset

  auto stage = [&](int bb, int t) {
#pragma unroll
    for (int i = 0; i < 4; ++i) {
      int c = i * 4 + wid;               // chunk 0..15 (8 rows, 1KB each)
      async_copy16(&As[bb][c * 512], Ab + (size_t)(c * 8 + srow) * K + t * 64 + sgc);
      async_copy16(&Bs[bb][c * 512], Bb + (size_t)(c * 8 + srow) * K + t * 64 + sgc);
    }
  };

  stage(0, 0);
  const int NT = K / 64;   // 16
  for (int t = 0; t < NT; ++t) {
    int bb = t & 1;
    int tn = (t + 1 < NT) ? t + 1 : t;   // clamp keeps vmcnt counts static
    stage(bb ^ 1, tn);                   // prefetch next tile
    WAIT_VM8();                          // this tile's 8 landed; next 8 flying
    BARRIER();
    bf16x8 af[4][2], bf[4][2];
#pragma unroll
    for (int mt = 0; mt < 4; ++mt) {
      const u16* base = &As[bb][(wm + mt * 16 + lm) * 64];
#pragma unroll
      for (int kh = 0; kh < 2; ++kh)
        af[mt][kh] = *reinterpret_cast<const bf16x8*>(base + (((kh * 4 + lq) ^ (lm & 7)) * 8));
    }
#pragma unroll
    for (int nt = 0; nt < 4; ++nt) {
      const u16* base = &Bs[bb][(wn + nt * 16 + lm) * 64];
#pragma unroll
      for (int kh = 0; kh < 2; ++kh)
        bf[nt][kh] = *reinterpret_cast<const bf16x8*>(base + (((kh * 4 + lq) ^ (lm & 7)) * 8));
    }
    if (qk) {
      // swapped operands: C' = C^T (row = n-dim, col = m-dim)
#pragma unroll
      for (int mt = 0; mt < 4; ++mt)
#pragma unroll
        for (int nt = 0; nt < 4; ++nt)
#pragma unroll
          for (int kh = 0; kh < 2; ++kh)
            acc[mt][nt] = __builtin_amdgcn_mfma_f32_16x16x32_bf16(bf[nt][kh], af[mt][kh],
                                                                  acc[mt][nt], 0, 0, 0);
    } else {
#pragma unroll
      for (int mt = 0; mt < 4; ++mt)
#pragma unroll
        for (int nt = 0; nt < 4; ++nt)
#pragma unroll
          for (int kh = 0; kh < 2; ++kh)
            acc[mt][nt] = __builtin_amdgcn_mfma_f32_16x16x32_bf16(af[mt][kh], bf[nt][kh],
                                                                  acc[mt][nt], 0, 0, 0);
    }
    LGKM0();                // this wave's reads of buf bb done...
    BARRIER();              // ...block-wide, before next iter overwrites it
  }
  WAIT_VM0();               // drain clamped tail prefetch before exit

  const float qscale = 0.18033688011112042f;  // 1/sqrt(64) * log2(e)
  if (qk) {
    // row = n (4 consecutive channels per lane), col = m (token)
    const float* bvec = (bn < 8) ? bQ : bK;
    u16* outp = (bn < 8) ? qo : ko;
    float scale = (bn < 8) ? qscale : 1.0f;
#pragma unroll
    for (int mt = 0; mt < 4; ++mt) {
#pragma unroll
      for (int nt = 0; nt < 4; ++nt) {
        int n0 = bn * 128 + wn + nt * 16 + lq * 4;
        int m  = bm * 128 + wm + mt * 16 + lm;
        int c0 = n0 & 1023;
        int h = c0 >> 6;
        int d0 = c0 & 63;
        int b = m >> 11;
        int tt = m & 2047;
        float4 ba = *reinterpret_cast<const float4*>(&b_attn[n0]);
        float4 bb = *reinterpret_cast<const float4*>(&bvec[c0]);
        u16 wb[4];
        wb[0] = f2bf((acc[mt][nt][0] + ba.x + bb.x) * scale);
        wb[1] = f2bf((acc[mt][nt][1] + ba.y + bb.y) * scale);
        wb[2] = f2bf((acc[mt][nt][2] + ba.z + bb.z) * scale);
        wb[3] = f2bf((acc[mt][nt][3] + ba.w + bb.w) * scale);
        *reinterpret_cast<uint2*>(&outp[((size_t)(b * NH_ + h) * T_ + tt) * D_ + d0]) =
            *reinterpret_cast<uint2*>(wb);
      }
    }
  } else {
    // V: row = m (4 consecutive tokens per lane), col = n -> uint2 into V^T
#pragma unroll
    for (int mt = 0; mt < 4; ++mt) {
#pragma unroll
      for (int nt = 0; nt < 4; ++nt) {
        int m0 = bm * 128 + wm + mt * 16 + lq * 4;
        int n = bn * 128 + wn + nt * 16 + lm;
        int c = n & 1023;
        int h = c >> 6;
        int d = c & 63;
        int b = m0 >> 11;
        int t0 = m0 & 2047;
        float bias = b_attn[n];
        u16 wb[4];
#pragma unroll
        for (int r = 0; r < 4; ++r) wb[r] = f2bf(acc[mt][nt][r] + bias);
        *reinterpret_cast<uint2*>(&vo[((size_t)(b * NH_ + h) * D_ + d) * T_ + t0]) =
            *reinterpret_cast<uint2*>(wb);
      }
    }
  }
}

// ---------------- Flash attention (R2 structure + latency-chain diet) ----------------
// Base = R2/R6 restore (measured 101.7-104.2 us). This round, register-only
// chain cuts (NO setprio, NO LDS change, barriers identical):
//  * const-ones colsum MFMA for lsum: o5 = mfma(ones, pb, o5) -> every row =
//    colsum(P). Deletes rs adds + 2 shfl_xor (~240cy serial DS) per qt2;
//    epilogue reads o5[qt2][0], no shuffle. Register constant, unlike R3's
//    LDS ones-row (which added ds_reads to the chain and regressed).
//  * defer-max THR=8: skip rescale unless tile max grew >8. P<=2^8, f32-safe
//    (R4 passed correctness with this).
//  * V fragments loaded right after S MFMAs (independent of softmax) so their
//    ~120cy DS latency hides under softmax instead of sitting on the PV path.
__global__ __launch_bounds__(256, 4) void attn_kernel(const u16* __restrict__ q,
                                                      const u16* __restrict__ k,
                                                      const u16* __restrict__ vt,
                                                      u16* __restrict__ y) {
  int tid = threadIdx.x;
  int w = tid >> 6, lane = tid & 63;
  int lm = lane & 15, lq = lane >> 4;

  __shared__ u16 Ks[2][64 * 64];   // [buf][key][d swizzled]    16 KB
  __shared__ u16 Vs[2][64 * 64];   // [buf][d][key swizzled]    16 KB

  int srow = lane >> 3;            // staging row within 8-row chunk
  int sg   = (lane & 7) ^ srow;    // swizzled 16B col-group

  // static balanced mapping (LPT)
  int idx = blockIdx.x;
  int c8 = idx & 255, jq = idx >> 8;
  int a = c8 & 7, gq = c8 >> 3;
  int qt, bh;
  if (jq == 0)      { qt = 15 - a; bh = gq; }
  else if (jq == 1) { qt = 8 + a;  bh = 32 + gq; }
  else if (jq == 2) { qt = 7 - a;  bh = gq; }
  else              { qt = a;      bh = 32 + gq; }

  int b = bh >> 4, h = bh & 15;
  const int klast = 2 * qt + 1;
  const int qrow0 = qt * 128 + w * 32;

  const u16* qb = q + ((size_t)bh * T_ + qrow0) * D_;
  const u16* kb = k + (size_t)bh * T_ * D_;
  const u16* vb = vt + (size_t)bh * D_ * T_;   // [d][t]

  auto stage_K = [&](int buf, int kbi) {
    const u16* gb = kb + (size_t)(kbi * 64) * 64;
#pragma unroll
    for (int j = 0; j < 2; ++j) {
      int c = w * 2 + j;
      async_copy16(&Ks[buf][c * 512], gb + (c * 8 + srow) * 64 + sg * 8);
    }
  };
  auto stage_V = [&](int buf, int kbi) {
    const u16* gb = vb + kbi * 64;
#pragma unroll
    for (int j = 0; j < 2; ++j) {
      int c = w * 2 + j;
      async_copy16(&Vs[buf][c * 512], gb + (size_t)(c * 8 + srow) * T_ + sg * 8);
    }
  };

  // Q as B-operand: lane n=q=lm, k=d (pre-scaled by 1/sqrt(D)*log2e)
  bf16x8 bq[2][2];
#pragma unroll
  for (int qt2 = 0; qt2 < 2; ++qt2) {
    const u16* qp = qb + (qt2 * 16 + lm) * D_ + lq * 8;
    bq[qt2][0] = *reinterpret_cast<const bf16x8*>(qp);
    bq[qt2][1] = *reinterpret_cast<const bf16x8*>(qp + 32);
  }

  // constant all-ones A-frag for the colsum MFMA
  const __bf16 one_ = (__bf16)1.0f;
  const bf16x8 ones = (bf16x8){one_, one_, one_, one_, one_, one_, one_, one_};

  f32x4 o[4][2], o5[2];
#pragma unroll
  for (int dt = 0; dt < 4; ++dt)
#pragma unroll
    for (int qt2 = 0; qt2 < 2; ++qt2) o[dt][qt2] = (f32x4){0.f, 0.f, 0.f, 0.f};
  o5[0] = (f32x4){0.f, 0.f, 0.f, 0.f};
  o5[1] = (f32x4){0.f, 0.f, 0.f, 0.f};
  float mprev[2] = {-1e30f, -1e30f};

  stage_K(0, 0); stage_V(0, 0);
  stage_K(1, 1); stage_V(1, 1);

  for (int kbi = 0; kbi <= klast; ++kbi) {
    int buf = kbi & 1;
    WAIT_VM4();                  // own share of tile kbi landed (kbi+1 flying)
    BARRIER();                   // all waves' shares landed

    // K frags: row=key=kt*16+lm, swizzled col-group
    bf16x8 kf[4][2];
#pragma unroll
    for (int kt = 0; kt < 4; ++kt) {
      const u16* base = &Ks[buf][(kt * 16 + lm) * 64];
      kf[kt][0] = *reinterpret_cast<const bf16x8*>(base + ((lq ^ (lm & 7)) * 8));
      kf[kt][1] = *reinterpret_cast<const bf16x8*>(base + (((4 + lq) ^ (lm & 7)) * 8));
    }

    // S^T[key][q]: lane (q=lm, lq) element r of s[kt] -> key kt*16+lq*4+r
    f32x4 s[4][2];
#pragma unroll
    for (int kt = 0; kt < 4; ++kt)
#pragma unroll
      for (int qt2 = 0; qt2 < 2; ++qt2) {
        f32x4 z = (f32x4){0.f, 0.f, 0.f, 0.f};
        z = __builtin_amdgcn_mfma_f32_16x16x32_bf16(kf[kt][0], bq[qt2][0], z, 0, 0, 0);
        z = __builtin_amdgcn_mfma_f32_16x16x32_bf16(kf[kt][1], bq[qt2][1], z, 0, 0, 0);
        s[kt][qt2] = z;
      }

    // V frags loaded NOW (independent of softmax) -- DS latency hides under
    // the softmax below instead of delaying PV.
    bf16x8 vf[4][2];
    {
      int r7 = lm & 7;
      int h4 = (lq & 1) * 4;
      int g0 = lq >> 1;
#pragma unroll
      for (int dt = 0; dt < 4; ++dt) {
        const u16* vbase = &Vs[buf][(dt * 16 + lm) * 64];
        union { u64 qd[2]; bf16x8 v; } t0, t1;
        t0.qd[0] = *reinterpret_cast<const u64*>(vbase + ((g0 ^ r7) * 8) + h4);
        t0.qd[1] = *reinterpret_cast<const u64*>(vbase + (((g0 + 2) ^ r7) * 8) + h4);
        t1.qd[0] = *reinterpret_cast<const u64*>(vbase + (((g0 + 4) ^ r7) * 8) + h4);
        t1.qd[1] = *reinterpret_cast<const u64*>(vbase + (((g0 + 6) ^ r7) * 8) + h4);
        vf[dt][0] = t0.v;
        vf[dt][1] = t1.v;
      }
    }

    bool maskt = (kbi * 64 + 63 > qrow0);
    bf16x8 pb[2][2];             // P as PV B-operand, permuted key order
#pragma unroll
    for (int qt2 = 0; qt2 < 2; ++qt2) {
      int qg = qrow0 + qt2 * 16 + lm;
      if (maskt) {
#pragma unroll
        for (int kt = 0; kt < 4; ++kt)
#pragma unroll
          for (int r = 0; r < 4; ++r) {
            int key = kbi * 64 + kt * 16 + lq * 4 + r;
            if (key > qg) s[kt][qt2][r] = -1e30f;
          }
      }
      float mx[4];
#pragma unroll
      for (int kt = 0; kt < 4; ++kt)
        mx[kt] = fmaxf(fmaxf(s[kt][qt2][0], s[kt][qt2][1]),
                       fmaxf(s[kt][qt2][2], s[kt][qt2][3]));
      float mval = fmaxf(fmaxf(mx[0], mx[1]), fmaxf(mx[2], mx[3]));
      mval = fmaxf(mval, __shfl_xor(mval, 16));
      mval = fmaxf(mval, __shfl_xor(mval, 32));
      // T13 defer-max: rescale only when the max grew by > 8
      float mold = mprev[qt2];
      if (__ballot(mval > mold + 8.f)) {
        float mnew = fmaxf(mold, mval);
        float alpha = __builtin_exp2f(mold - mnew);
#pragma unroll
        for (int dt = 0; dt < 4; ++dt) o[dt][qt2] *= alpha;
        o5[qt2] *= alpha;
        mprev[qt2] = mnew;
      }
      float m = mprev[qt2];
      unsigned pw[8];
#pragma unroll
      for (int kt = 0; kt < 4; ++kt) {
        unsigned pu[4];
#pragma unroll
        for (int r = 0; r < 4; ++r) {
          float p = __builtin_exp2f(s[kt][qt2][r] - m);
          union { float f; unsigned u; } cc; cc.f = p;
          pu[r] = cc.u;
        }
        pw[kt * 2]     = __builtin_amdgcn_perm(pu[1], pu[0], 0x07060302u);
        pw[kt * 2 + 1] = __builtin_amdgcn_perm(pu[3], pu[2], 0x07060302u);
      }
      union { unsigned u[4]; bf16x8 v; } b0, b1;
#pragma unroll
      for (int t = 0; t < 4; ++t) { b0.u[t] = pw[t]; b1.u[t] = pw[4 + t]; }
      pb[qt2][0] = b0.v;
      pb[qt2][1] = b1.v;
    }

    // PV (+ const-ones colsum) from the pre-loaded V registers
#pragma unroll
    for (int dt = 0; dt < 4; ++dt)
#pragma unroll
      for (int qt2 = 0; qt2 < 2; ++qt2) {
        o[dt][qt2] = __builtin_amdgcn_mfma_f32_16x16x32_bf16(vf[dt][0], pb[qt2][0], o[dt][qt2], 0, 0, 0);
        o[dt][qt2] = __builtin_amdgcn_mfma_f32_16x16x32_bf16(vf[dt][1], pb[qt2][1], o[dt][qt2], 0, 0, 0);
      }
#pragma unroll
    for (int qt2 = 0; qt2 < 2; ++qt2) {
      o5[qt2] = __builtin_amdgcn_mfma_f32_16x16x32_bf16(ones, pb[qt2][0], o5[qt2], 0, 0, 0);
      o5[qt2] = __builtin_amdgcn_mfma_f32_16x16x32_bf16(ones, pb[qt2][1], o5[qt2], 0, 0, 0);
    }

    BARRIER();                   // all waves done reading buf before overwrite
    int nk = (kbi + 2 <= klast) ? kbi + 2 : klast;
    stage_K(buf, nk); stage_V(buf, nk);
  }

  WAIT_VM0();  // drain tail prefetches before LDS is freed at endpgm

  // write y[b][t=q][h][d]; every o5 row holds colsum(P) for col=q=lm, so
  // lsum = o5[qt2][0] in every lane -- no shuffle needed.
#pragma unroll
  for (int qt2 = 0; qt2 < 2; ++qt2) {
    float inv = 1.f / o5[qt2][0];
    int qg = qrow0 + qt2 * 16 + lm;
#pragma unroll
    for (int dt = 0; dt < 4; ++dt) {
      u16 wb[4];
#pragma unroll
      for (int r = 0; r < 4; ++r) wb[r] = f2bf(o[dt][qt2][r] * inv);
      int d = dt * 16 + lq * 4;
      *reinterpret_cast<uint2*>(&y[((size_t)(b * T_ + qg) * NH_ + h) * D_ + d]) =
          *reinterpret_cast<uint2*>(wb);
    }
  }
}

// ---------------- Proj GEMM: 128x128, BK=64, prefetched 2-phase ----------------
// Swapped-operand epilogue (mirrors the verified qkv win): lane holds 4
// consecutive n in its r-quad -> float4 stores + float4 bias loads.
__global__ __launch_bounds__(256, 2) void gemm_proj(const u16* __restrict__ A,
                                                    const u16* __restrict__ Bt,
                                                    const float* __restrict__ b_proj,
                                                    float* __restrict__ out) {
  const int K = C_, N = C_;
  int bid = blockIdx.x;
  int wg = (bid & 7) * 64 + (bid >> 3);   // 512 = 8 x 64 bijective
  int bm = wg / 8, bn = wg % 8;

  int tid = threadIdx.x;
  int wid = tid >> 6, lane = tid & 63;
  int lm = lane & 15, lq = lane >> 4;
  int wm = (wid >> 1) * 64, wn = (wid & 1) * 64;

  __shared__ u16 As[2][128 * 64];
  __shared__ u16 Bs[2][128 * 64];

  f32x4 acc[4][4];
#pragma unroll
  for (int i = 0; i < 4; ++i)
#pragma unroll
    for (int j = 0; j < 4; ++j) acc[i][j] = (f32x4){0.f, 0.f, 0.f, 0.f};

  const u16* Ab = A + (size_t)(bm * 128) * K;
  const u16* Bb = Bt + (size_t)(bn * 128) * K;
  int srow = lane >> 3;
  int sgc  = ((lane & 7) ^ srow) * 8;

  auto stage = [&](int bb, int t) {
#pragma unroll
    for (int i = 0; i < 4; ++i) {
      int c = i * 4 + wid;
      async_copy16(&As[bb][c * 512], Ab + (size_t)(c * 8 + srow) * K + t * 64 + sgc);
      async_copy16(&Bs[bb][c * 512], Bb + (size_t)(c * 8 + srow) * K + t * 64 + sgc);
    }
  };

  stage(0, 0);
  const int NT = K / 64;   // 16
  for (int t = 0; t < NT; ++t) {
    int bb = t & 1;
    int tn = (t + 1 < NT) ? t + 1 : t;
    stage(bb ^ 1, tn);
    WAIT_VM8();
    BARRIER();
    bf16x8 af[4][2], bf[4][2];
#pragma unroll
    for (int mt = 0; mt < 4; ++mt) {
      const u16* base = &As[bb][(wm + mt * 16 + lm) * 64];
#pragma unroll
      for (int kh = 0; kh < 2; ++kh)
        af[mt][kh] = *reinterpret_cast<const bf16x8*>(base + (((kh * 4 + lq) ^ (lm & 7)) * 8));
    }
#pragma unroll
    for (int nt = 0; nt < 4; ++nt) {
      const u16* base = &Bs[bb][(wn + nt * 16 + lm) * 64];
#pragma unroll
      for (int kh = 0; kh < 2; ++kh)
        bf[nt][kh] = *reinterpret_cast<const bf16x8*>(base + (((kh * 4 + lq) ^ (lm & 7)) * 8));
    }
    // swapped operands: row = n-dim, col = m-dim
#pragma unroll
    for (int mt = 0; mt < 4; ++mt)
#pragma unroll
      for (int nt = 0; nt < 4; ++nt)
#pragma unroll
        for (int kh = 0; kh < 2; ++kh)
          acc[mt][nt] = __builtin_amdgcn_mfma_f32_16x16x32_bf16(bf[nt][kh], af[mt][kh],
                                                                acc[mt][nt], 0, 0, 0);
    LGKM0();
    BARRIER();
  }
  WAIT_VM0();

#pragma unroll
  for (int mt = 0; mt < 4; ++mt) {
#pragma unroll
    for (int nt = 0; nt < 4; ++nt) {
      int n0 = bn * 128 + wn + nt * 16 + lq * 4;
      int m  = bm * 128 + wm + mt * 16 + lm;
      float4 bp = *reinterpret_cast<const float4*>(&b_proj[n0]);
      float4 res;
      res.x = acc[mt][nt][0] + bp.x;
      res.y = acc[mt][nt][1] + bp.y;
      res.z = acc[mt][nt][2] + bp.z;
      res.w = acc[mt][nt][3] + bp.w;
      *reinterpret_cast<float4*>(&out[(size_t)m * N + n0]) = res;
    }
  }
}

extern "C" void kernel_launch(void* const* d_in, const int* in_sizes, int n_in,
                              void* d_out, int out_size, void* d_ws, size_t ws_size,
                              hipStream_t stream) {
  const float* x      = (const float*)d_in[0];
  const float* W_attn = (const float*)d_in[1];
  const float* b_attn = (const float*)d_in[2];
  const float* bQ     = (const float*)d_in[3];
  const float* bK     = (const float*)d_in[4];
  const float* W_proj = (const float*)d_in[5];
  const float* b_proj = (const float*)d_in[6];
  float* out = (float*)d_out;

  char* ws = (char*)d_ws;
  u16* xb  = (u16*)(ws);                              // [8192][1024]      16 MB
  u16* WaT = (u16*)(ws + 16777216);                   // [3072][1024]       6 MB
  u16* WpT = (u16*)(ws + 23068672);                   // [1024][1024]       2 MB
  u16* qw  = (u16*)(ws + 25165824);                   // [B,NH,T,D] scaled 16 MB
  u16* kw  = (u16*)(ws + 41943040);                   // [B,NH,T,D]        16 MB
  u16* vw  = (u16*)(ws + 58720256);                   // [B,NH,D,T] (V^T)  16 MB
  u16* yw  = (u16*)(ws + 75497472);                   // [8192][1024]      16 MB

  conv_bf16<<<M_ * C_ / (4 * 256), 256, 0, stream>>>(x, xb, M_ * C_);
  {
    dim3 g(N_QKV / 32, C_ / 32);
    transpose_bf16<<<g, 256, 0, stream>>>(W_attn, WaT, C_, N_QKV);
  }
  {
    dim3 g(C_ / 32, C_ / 32);
    transpose_bf16<<<g, 256, 0, stream>>>(W_proj, WpT, C_, C_);
  }
  gemm_qkv<<<(M_ / 128) * (N_QKV / 128), 256, 0, stream>>>(xb, WaT, b_attn, bQ, bK, qw, kw, vw);
  attn_kernel<<<ATTN_BLOCKS, 256, 0, stream>>>(qw, kw, vw, yw);
  gemm_proj<<<(M_ / 128) * (C_ / 128), 256, 0, stream>>>(yw, WpT, b_proj, out);
}

// Round 8
// 289.473 us; speedup vs baseline: 1.3691x; 1.3691x over previous
//
#include <hip/hip_runtime.h>

typedef unsigned short u16;
typedef unsigned int u32;
typedef unsigned long long u64;
typedef __bf16 bf16x8 __attribute__((ext_vector_type(8)));
typedef float f32x4 __attribute__((ext_vector_type(4)));

#define B_  4
#define T_  2048
#define C_  1024
#define NH_ 16
#define D_  64
#define M_  (B_*T_)          // 8192
#define N_QKV (3*C_)         // 3072

#define ATTN_BLOCKS 1024     // one (bh, 128-row qtile) per block, 4 blocks/CU

// raw barrier + static waitcnt (no vmcnt(0) drain -- keeps prefetch in flight)
#define BARRIER()  __asm__ __volatile__("s_barrier" ::: "memory")
#define WAIT_VM4() __asm__ __volatile__("s_waitcnt vmcnt(4)" ::: "memory")
#define WAIT_VM8() __asm__ __volatile__("s_waitcnt vmcnt(8)" ::: "memory")
#define WAIT_VM0() __asm__ __volatile__("s_waitcnt vmcnt(0)" ::: "memory")
#define LGKM0()    __asm__ __volatile__("s_waitcnt lgkmcnt(0)" ::: "memory")

// async global->LDS, 16B per lane. LDS dest = wave-uniform base + lane*16
__device__ __forceinline__ void async_copy16(void* lds, const void* gptr) {
  __builtin_amdgcn_global_load_lds(
      (const __attribute__((address_space(1))) u32*)gptr,
      (__attribute__((address_space(3))) u32*)(u32)(uintptr_t)lds,
      16, 0, 0);
}

// RNE float -> bf16 bits
__device__ __forceinline__ u16 f2bf(float f) {
  union { float f; unsigned u; } c; c.f = f;
  unsigned u = c.u;
  unsigned r = (u + 0x7fffu + ((u >> 16) & 1u)) >> 16;
  return (u16)r;
}

// ---------------- elementwise fp32 -> bf16 ----------------
__global__ __launch_bounds__(256) void conv_bf16(const float* __restrict__ in,
                                                 u16* __restrict__ out, int n) {
  int i = (blockIdx.x * 256 + threadIdx.x) * 4;
  if (i < n) {
    float4 f = *reinterpret_cast<const float4*>(in + i);
    u16 o[4] = { f2bf(f.x), f2bf(f.y), f2bf(f.z), f2bf(f.w) };
    *reinterpret_cast<uint2*>(out + i) = *reinterpret_cast<uint2*>(o);
  }
}

// ---------------- transpose fp32 [K][N] -> bf16 [N][K] ----------------
__global__ __launch_bounds__(256) void transpose_bf16(const float* __restrict__ in,
                                                      u16* __restrict__ out,
                                                      int K, int N) {
  __shared__ float tile[32][33];
  int bi = blockIdx.y;
  int bj = blockIdx.x;
  int tx = threadIdx.x & 31;
  int ty = threadIdx.x >> 5;
#pragma unroll
  for (int i = 0; i < 4; ++i) {
    int row = ty + i * 8;
    tile[row][tx] = in[(bi * 32 + row) * N + bj * 32 + tx];
  }
  __syncthreads();
#pragma unroll
  for (int i = 0; i < 4; ++i) {
    int row = ty + i * 8;
    out[(bj * 32 + row) * K + bi * 32 + tx] = f2bf(tile[tx][row]);
  }
}

// ---------------- QKV GEMM: 128x128, BK=64, prefetched 2-phase ----------------
// Q/K blocks (bn<16, uniform per block) compute the TRANSPOSED C fragment by
// swapping the MFMA operands -- lane holds 4 consecutive channels d in its
// r-quad -> one uint2 store; bias/bQ/bK become aligned float4 loads.
// (verified R6: qkv ~104 -> ~78 us)
__global__ __launch_bounds__(256, 2) void gemm_qkv(const u16* __restrict__ A,
                                                   const u16* __restrict__ Bt,
                                                   const float* __restrict__ b_attn,
                                                   const float* __restrict__ bQ,
                                                   const float* __restrict__ bK,
                                                   u16* __restrict__ qo,
                                                   u16* __restrict__ ko,
                                                   u16* __restrict__ vo) {
  const int K = C_;
  // bijective XCD swizzle: 1536 = 8 x 192; bm-major inside a chunk
  int bid = blockIdx.x;
  int wg = (bid & 7) * 192 + (bid >> 3);
  int bm = wg / 24, bn = wg % 24;
  const bool qk = (bn < 16);          // Q or K block (uniform)

  int tid = threadIdx.x;
  int wid = tid >> 6, lane = tid & 63;
  int lm = lane & 15, lq = lane >> 4;
  int wm = (wid >> 1) * 64, wn = (wid & 1) * 64;

  __shared__ u16 As[2][128 * 64];
  __shared__ u16 Bs[2][128 * 64];

  f32x4 acc[4][4];
#pragma unroll
  for (int i = 0; i < 4; ++i)
#pragma unroll
    for (int j = 0; j < 4; ++j) acc[i][j] = (f32x4){0.f, 0.f, 0.f, 0.f};

  const u16* Ab = A + (size_t)(bm * 128) * K;
  const u16* Bb = Bt + (size_t)(bn * 128) * K;
  int srow = lane >> 3;                  // row within 8-row chunk
  int sgc  = ((lane & 7) ^ srow) * 8;    // pre-swizzled global u16 col offset

  auto stage = [&](int bb, int t) {
#pragma unroll
    for (int i = 0; i < 4; ++i) {
      int c = i * 4 + wid;               // chunk 0..15 (8 rows, 1KB each)
      async_copy16(&As[bb][c * 512], Ab + (size_t)(c * 8 + srow) * K + t * 64 + sgc);
      async_copy16(&Bs[bb][c * 512], Bb + (size_t)(c * 8 + srow) * K + t * 64 + sgc);
    }
  };

  stage(0, 0);
  const int NT = K / 64;   // 16
  for (int t = 0; t < NT; ++t) {
    int bb = t & 1;
    int tn = (t + 1 < NT) ? t + 1 : t;   // clamp keeps vmcnt counts static
    stage(bb ^ 1, tn);                   // prefetch next tile
    WAIT_VM8();                          // this tile's 8 landed; next 8 flying
    BARRIER();
    bf16x8 af[4][2], bf[4][2];
#pragma unroll
    for (int mt = 0; mt < 4; ++mt) {
      const u16* base = &As[bb][(wm + mt * 16 + lm) * 64];
#pragma unroll
      for (int kh = 0; kh < 2; ++kh)
        af[mt][kh] = *reinterpret_cast<const bf16x8*>(base + (((kh * 4 + lq) ^ (lm & 7)) * 8));
    }
#pragma unroll
    for (int nt = 0; nt < 4; ++nt) {
      const u16* base = &Bs[bb][(wn + nt * 16 + lm) * 64];
#pragma unroll
      for (int kh = 0; kh < 2; ++kh)
        bf[nt][kh] = *reinterpret_cast<const bf16x8*>(base + (((kh * 4 + lq) ^ (lm & 7)) * 8));
    }
    if (qk) {
      // swapped operands: C' = C^T (row = n-dim, col = m-dim)
#pragma unroll
      for (int mt = 0; mt < 4; ++mt)
#pragma unroll
        for (int nt = 0; nt < 4; ++nt)
#pragma unroll
          for (int kh = 0; kh < 2; ++kh)
            acc[mt][nt] = __builtin_amdgcn_mfma_f32_16x16x32_bf16(bf[nt][kh], af[mt][kh],
                                                                  acc[mt][nt], 0, 0, 0);
    } else {
#pragma unroll
      for (int mt = 0; mt < 4; ++mt)
#pragma unroll
        for (int nt = 0; nt < 4; ++nt)
#pragma unroll
          for (int kh = 0; kh < 2; ++kh)
            acc[mt][nt] = __builtin_amdgcn_mfma_f32_16x16x32_bf16(af[mt][kh], bf[nt][kh],
                                                                  acc[mt][nt], 0, 0, 0);
    }
    LGKM0();                // this wave's reads of buf bb done...
    BARRIER();              // ...block-wide, before next iter overwrites it
  }
  WAIT_VM0();               // drain clamped tail prefetch before exit

  const float qscale = 0.18033688011112042f;  // 1/sqrt(64) * log2(e)
  if (qk) {
    // row = n (4 consecutive channels per lane), col = m (token)
    const float* bvec = (bn < 8) ? bQ : bK;
    u16* outp = (bn < 8) ? qo : ko;
    float scale = (bn < 8) ? qscale : 1.0f;
#pragma unroll
    for (int mt = 0; mt < 4; ++mt) {
#pragma unroll
      for (int nt = 0; nt < 4; ++nt) {
        int n0 = bn * 128 + wn + nt * 16 + lq * 4;
        int m  = bm * 128 + wm + mt * 16 + lm;
        int c0 = n0 & 1023;
        int h = c0 >> 6;
        int d0 = c0 & 63;
        int b = m >> 11;
        int tt = m & 2047;
        float4 ba = *reinterpret_cast<const float4*>(&b_attn[n0]);
        float4 bb = *reinterpret_cast<const float4*>(&bvec[c0]);
        u16 wb[4];
        wb[0] = f2bf((acc[mt][nt][0] + ba.x + bb.x) * scale);
        wb[1] = f2bf((acc[mt][nt][1] + ba.y + bb.y) * scale);
        wb[2] = f2bf((acc[mt][nt][2] + ba.z + bb.z) * scale);
        wb[3] = f2bf((acc[mt][nt][3] + ba.w + bb.w) * scale);
        *reinterpret_cast<uint2*>(&outp[((size_t)(b * NH_ + h) * T_ + tt) * D_ + d0]) =
            *reinterpret_cast<uint2*>(wb);
      }
    }
  } else {
    // V: row = m (4 consecutive tokens per lane), col = n -> uint2 into V^T
#pragma unroll
    for (int mt = 0; mt < 4; ++mt) {
#pragma unroll
      for (int nt = 0; nt < 4; ++nt) {
        int m0 = bm * 128 + wm + mt * 16 + lq * 4;
        int n = bn * 128 + wn + nt * 16 + lm;
        int c = n & 1023;
        int h = c >> 6;
        int d = c & 63;
        int b = m0 >> 11;
        int t0 = m0 & 2047;
        float bias = b_attn[n];
        u16 wb[4];
#pragma unroll
        for (int r = 0; r < 4; ++r) wb[r] = f2bf(acc[mt][nt][r] + bias);
        *reinterpret_cast<uint2*>(&vo[((size_t)(b * NH_ + h) * D_ + d) * T_ + t0]) =
            *reinterpret_cast<uint2*>(wb);
      }
    }
  }
}

// ---------------- Flash attention (byte-exact R6 restore: measured 101.7 us) ----------------
// 1024 blocks, one (bh, 128-row q-tile) item each, 4 blocks/CU (32 KB LDS).
// Static LPT-balanced mapping. P never touches LDS. Per iter:
//   wait vmcnt(4); s_barrier; S MFMA + softmax (in-reg) + PV MFMA from buf;
//   s_barrier; stage tile kbi+2 (clamped -> static vmcnt counts).
// DO NOT add register state to this kernel without checking VGPR count:
// R7's V-hoist + colsum-MFMA additions spilled to scratch (WRITE_SIZE 22->249
// MB) and cost 2x. The kernel is register-saturated at 64 VGPR.
__global__ __launch_bounds__(256, 4) void attn_kernel(const u16* __restrict__ q,
                                                      const u16* __restrict__ k,
                                                      const u16* __restrict__ vt,
                                                      u16* __restrict__ y) {
  int tid = threadIdx.x;
  int w = tid >> 6, lane = tid & 63;
  int lm = lane & 15, lq = lane >> 4;

  __shared__ u16 Ks[2][64 * 64];   // [buf][key][d swizzled]    16 KB
  __shared__ u16 Vs[2][64 * 64];   // [buf][d][key swizzled]    16 KB

  int srow = lane >> 3;            // staging row within 8-row chunk
  int sg   = (lane & 7) ^ srow;    // swizzled 16B col-group

  // static balanced mapping (LPT)
  int idx = blockIdx.x;
  int c8 = idx & 255, jq = idx >> 8;
  int a = c8 & 7, gq = c8 >> 3;
  int qt, bh;
  if (jq == 0)      { qt = 15 - a; bh = gq; }
  else if (jq == 1) { qt = 8 + a;  bh = 32 + gq; }
  else if (jq == 2) { qt = 7 - a;  bh = gq; }
  else              { qt = a;      bh = 32 + gq; }

  int b = bh >> 4, h = bh & 15;
  const int klast = 2 * qt + 1;
  const int qrow0 = qt * 128 + w * 32;

  const u16* qb = q + ((size_t)bh * T_ + qrow0) * D_;
  const u16* kb = k + (size_t)bh * T_ * D_;
  const u16* vb = vt + (size_t)bh * D_ * T_;   // [d][t]

  auto stage_K = [&](int buf, int kbi) {
    const u16* gb = kb + (size_t)(kbi * 64) * 64;
#pragma unroll
    for (int j = 0; j < 2; ++j) {
      int c = w * 2 + j;
      async_copy16(&Ks[buf][c * 512], gb + (c * 8 + srow) * 64 + sg * 8);
    }
  };
  auto stage_V = [&](int buf, int kbi) {
    const u16* gb = vb + kbi * 64;
#pragma unroll
    for (int j = 0; j < 2; ++j) {
      int c = w * 2 + j;
      async_copy16(&Vs[buf][c * 512], gb + (size_t)(c * 8 + srow) * T_ + sg * 8);
    }
  };

  // Q as B-operand: lane n=q=lm, k=d (pre-scaled by 1/sqrt(D)*log2e)
  bf16x8 bq[2][2];
#pragma unroll
  for (int qt2 = 0; qt2 < 2; ++qt2) {
    const u16* qp = qb + (qt2 * 16 + lm) * D_ + lq * 8;
    bq[qt2][0] = *reinterpret_cast<const bf16x8*>(qp);
    bq[qt2][1] = *reinterpret_cast<const bf16x8*>(qp + 32);
  }

  f32x4 o[4][2];
#pragma unroll
  for (int dt = 0; dt < 4; ++dt)
#pragma unroll
    for (int qt2 = 0; qt2 < 2; ++qt2) o[dt][qt2] = (f32x4){0.f, 0.f, 0.f, 0.f};
  float mprev[2] = {-1e30f, -1e30f}, lsum[2] = {0.f, 0.f};

  stage_K(0, 0); stage_V(0, 0);
  stage_K(1, 1); stage_V(1, 1);

  for (int kbi = 0; kbi <= klast; ++kbi) {
    int buf = kbi & 1;
    WAIT_VM4();                  // own share of tile kbi landed (kbi+1 flying)
    BARRIER();                   // all waves' shares landed

    // K frags: row=key=kt*16+lm, swizzled col-group
    bf16x8 kf[4][2];
#pragma unroll
    for (int kt = 0; kt < 4; ++kt) {
      const u16* base = &Ks[buf][(kt * 16 + lm) * 64];
      kf[kt][0] = *reinterpret_cast<const bf16x8*>(base + ((lq ^ (lm & 7)) * 8));
      kf[kt][1] = *reinterpret_cast<const bf16x8*>(base + (((4 + lq) ^ (lm & 7)) * 8));
    }

    // S^T[key][q]: lane (q=lm, lq) element r of s[kt] -> key kt*16+lq*4+r
    f32x4 s[4][2];
#pragma unroll
    for (int kt = 0; kt < 4; ++kt)
#pragma unroll
      for (int qt2 = 0; qt2 < 2; ++qt2) {
        f32x4 z = (f32x4){0.f, 0.f, 0.f, 0.f};
        z = __builtin_amdgcn_mfma_f32_16x16x32_bf16(kf[kt][0], bq[qt2][0], z, 0, 0, 0);
        z = __builtin_amdgcn_mfma_f32_16x16x32_bf16(kf[kt][1], bq[qt2][1], z, 0, 0, 0);
        s[kt][qt2] = z;
      }

    bool maskt = (kbi * 64 + 63 > qrow0);
    bf16x8 pb[2][2];             // P as PV B-operand, permuted key order
#pragma unroll
    for (int qt2 = 0; qt2 < 2; ++qt2) {
      int qg = qrow0 + qt2 * 16 + lm;
      if (maskt) {
#pragma unroll
        for (int kt = 0; kt < 4; ++kt)
#pragma unroll
          for (int r = 0; r < 4; ++r) {
            int key = kbi * 64 + kt * 16 + lq * 4 + r;
            if (key > qg) s[kt][qt2][r] = -1e30f;
          }
      }
      float mx[4];
#pragma unroll
      for (int kt = 0; kt < 4; ++kt)
        mx[kt] = fmaxf(fmaxf(s[kt][qt2][0], s[kt][qt2][1]),
                       fmaxf(s[kt][qt2][2], s[kt][qt2][3]));
      float mval = fmaxf(fmaxf(mx[0], mx[1]), fmaxf(mx[2], mx[3]));
      mval = fmaxf(mval, __shfl_xor(mval, 16));
      mval = fmaxf(mval, __shfl_xor(mval, 32));
      float mold = mprev[qt2];
      float mnew = fmaxf(mold, mval);
      unsigned long long upd = __ballot(mval > mold);
      if (upd) {
        float alpha = __builtin_exp2f(mold - mnew);
        lsum[qt2] *= alpha;
#pragma unroll
        for (int dt = 0; dt < 4; ++dt) o[dt][qt2] *= alpha;
        mprev[qt2] = mnew;
      }
      float rs = 0.f;
      unsigned pw[8];
#pragma unroll
      for (int kt = 0; kt < 4; ++kt) {
        unsigned pu[4];
#pragma unroll
        for (int r = 0; r < 4; ++r) {
          float p = __builtin_exp2f(s[kt][qt2][r] - mnew);
          rs += p;
          union { float f; unsigned u; } cc; cc.f = p;
          pu[r] = cc.u;
        }
        pw[kt * 2]     = __builtin_amdgcn_perm(pu[1], pu[0], 0x07060302u);
        pw[kt * 2 + 1] = __builtin_amdgcn_perm(pu[3], pu[2], 0x07060302u);
      }
      rs += __shfl_xor(rs, 16);
      rs += __shfl_xor(rs, 32);
      lsum[qt2] += rs;
      union { unsigned u[4]; bf16x8 v; } b0, b1;
#pragma unroll
      for (int t = 0; t < 4; ++t) { b0.u[t] = pw[t]; b1.u[t] = pw[4 + t]; }
      pb[qt2][0] = b0.v;
      pb[qt2][1] = b1.v;
    }

    // PV with the SAME permuted k-slot->key map on the V (A) operand
    {
      int r7 = lm & 7;
      int h4 = (lq & 1) * 4;
      int g0 = lq >> 1;
#pragma unroll
      for (int dt = 0; dt < 4; ++dt) {
        const u16* vbase = &Vs[buf][(dt * 16 + lm) * 64];
        union { u64 qd[2]; bf16x8 v; } t0, t1;
        t0.qd[0] = *reinterpret_cast<const u64*>(vbase + ((g0 ^ r7) * 8) + h4);
        t0.qd[1] = *reinterpret_cast<const u64*>(vbase + (((g0 + 2) ^ r7) * 8) + h4);
        t1.qd[0] = *reinterpret_cast<const u64*>(vbase + (((g0 + 4) ^ r7) * 8) + h4);
        t1.qd[1] = *reinterpret_cast<const u64*>(vbase + (((g0 + 6) ^ r7) * 8) + h4);
#pragma unroll
        for (int qt2 = 0; qt2 < 2; ++qt2) {
          o[dt][qt2] = __builtin_amdgcn_mfma_f32_16x16x32_bf16(t0.v, pb[qt2][0], o[dt][qt2], 0, 0, 0);
          o[dt][qt2] = __builtin_amdgcn_mfma_f32_16x16x32_bf16(t1.v, pb[qt2][1], o[dt][qt2], 0, 0, 0);
        }
      }
    }

    BARRIER();                   // all waves done reading buf before overwrite
    int nk = (kbi + 2 <= klast) ? kbi + 2 : klast;
    stage_K(buf, nk); stage_V(buf, nk);
  }

  WAIT_VM0();  // drain tail prefetches before LDS is freed at endpgm

  // write y[b][t=q][h][d]; O^T C-layout: col=q=lm, row=d=dt*16+lq*4+r -> 8B stores
#pragma unroll
  for (int qt2 = 0; qt2 < 2; ++qt2) {
    float inv = 1.f / lsum[qt2];
    int qg = qrow0 + qt2 * 16 + lm;
#pragma unroll
    for (int dt = 0; dt < 4; ++dt) {
      u16 wb[4];
#pragma unroll
      for (int r = 0; r < 4; ++r) wb[r] = f2bf(o[dt][qt2][r] * inv);
      int d = dt * 16 + lq * 4;
      *reinterpret_cast<uint2*>(&y[((size_t)(b * T_ + qg) * NH_ + h) * D_ + d]) =
          *reinterpret_cast<uint2*>(wb);
    }
  }
}

// ---------------- Proj GEMM: 128x128, BK=64, prefetched 2-phase ----------------
// Swapped-operand epilogue (mirrors the verified qkv win): lane holds 4
// consecutive n in its r-quad -> float4 stores + float4 bias loads.
__global__ __launch_bounds__(256, 2) void gemm_proj(const u16* __restrict__ A,
                                                    const u16* __restrict__ Bt,
                                                    const float* __restrict__ b_proj,
                                                    float* __restrict__ out) {
  const int K = C_, N = C_;
  int bid = blockIdx.x;
  int wg = (bid & 7) * 64 + (bid >> 3);   // 512 = 8 x 64 bijective
  int bm = wg / 8, bn = wg % 8;

  int tid = threadIdx.x;
  int wid = tid >> 6, lane = tid & 63;
  int lm = lane & 15, lq = lane >> 4;
  int wm = (wid >> 1) * 64, wn = (wid & 1) * 64;

  __shared__ u16 As[2][128 * 64];
  __shared__ u16 Bs[2][128 * 64];

  f32x4 acc[4][4];
#pragma unroll
  for (int i = 0; i < 4; ++i)
#pragma unroll
    for (int j = 0; j < 4; ++j) acc[i][j] = (f32x4){0.f, 0.f, 0.f, 0.f};

  const u16* Ab = A + (size_t)(bm * 128) * K;
  const u16* Bb = Bt + (size_t)(bn * 128) * K;
  int srow = lane >> 3;
  int sgc  = ((lane & 7) ^ srow) * 8;

  auto stage = [&](int bb, int t) {
#pragma unroll
    for (int i = 0; i < 4; ++i) {
      int c = i * 4 + wid;
      async_copy16(&As[bb][c * 512], Ab + (size_t)(c * 8 + srow) * K + t * 64 + sgc);
      async_copy16(&Bs[bb][c * 512], Bb + (size_t)(c * 8 + srow) * K + t * 64 + sgc);
    }
  };

  stage(0, 0);
  const int NT = K / 64;   // 16
  for (int t = 0; t < NT; ++t) {
    int bb = t & 1;
    int tn = (t + 1 < NT) ? t + 1 : t;
    stage(bb ^ 1, tn);
    WAIT_VM8();
    BARRIER();
    bf16x8 af[4][2], bf[4][2];
#pragma unroll
    for (int mt = 0; mt < 4; ++mt) {
      const u16* base = &As[bb][(wm + mt * 16 + lm) * 64];
#pragma unroll
      for (int kh = 0; kh < 2; ++kh)
        af[mt][kh] = *reinterpret_cast<const bf16x8*>(base + (((kh * 4 + lq) ^ (lm & 7)) * 8));
    }
#pragma unroll
    for (int nt = 0; nt < 4; ++nt) {
      const u16* base = &Bs[bb][(wn + nt * 16 + lm) * 64];
#pragma unroll
      for (int kh = 0; kh < 2; ++kh)
        bf[nt][kh] = *reinterpret_cast<const bf16x8*>(base + (((kh * 4 + lq) ^ (lm & 7)) * 8));
    }
    // swapped operands: row = n-dim, col = m-dim
#pragma unroll
    for (int mt = 0; mt < 4; ++mt)
#pragma unroll
      for (int nt = 0; nt < 4; ++nt)
#pragma unroll
        for (int kh = 0; kh < 2; ++kh)
          acc[mt][nt] = __builtin_amdgcn_mfma_f32_16x16x32_bf16(bf[nt][kh], af[mt][kh],
                                                                acc[mt][nt], 0, 0, 0);
    LGKM0();
    BARRIER();
  }
  WAIT_VM0();

#pragma unroll
  for (int mt = 0; mt < 4; ++mt) {
#pragma unroll
    for (int nt = 0; nt < 4; ++nt) {
      int n0 = bn * 128 + wn + nt * 16 + lq * 4;
      int m  = bm * 128 + wm + mt * 16 + lm;
      float4 bp = *reinterpret_cast<const float4*>(&b_proj[n0]);
      float4 res;
      res.x = acc[mt][nt][0] + bp.x;
      res.y = acc[mt][nt][1] + bp.y;
      res.z = acc[mt][nt][2] + bp.z;
      res.w = acc[mt][nt][3] + bp.w;
      *reinterpret_cast<float4*>(&out[(size_t)m * N + n0]) = res;
    }
  }
}

extern "C" void kernel_launch(void* const* d_in, const int* in_sizes, int n_in,
                              void* d_out, int out_size, void* d_ws, size_t ws_size,
                              hipStream_t stream) {
  const float* x      = (const float*)d_in[0];
  const float* W_attn = (const float*)d_in[1];
  const float* b_attn = (const float*)d_in[2];
  const float* bQ     = (const float*)d_in[3];
  const float* bK     = (const float*)d_in[4];
  const float* W_proj = (const float*)d_in[5];
  const float* b_proj = (const float*)d_in[6];
  float* out = (float*)d_out;

  char* ws = (char*)d_ws;
  u16* xb  = (u16*)(ws);                              // [8192][1024]      16 MB
  u16* WaT = (u16*)(ws + 16777216);                   // [3072][1024]       6 MB
  u16* WpT = (u16*)(ws + 23068672);                   // [1024][1024]       2 MB
  u16* qw  = (u16*)(ws + 25165824);                   // [B,NH,T,D] scaled 16 MB
  u16* kw  = (u16*)(ws + 41943040);                   // [B,NH,T,D]        16 MB
  u16* vw  = (u16*)(ws + 58720256);                   // [B,NH,D,T] (V^T)  16 MB
  u16* yw  = (u16*)(ws + 75497472);                   // [8192][1024]      16 MB

  conv_bf16<<<M_ * C_ / (4 * 256), 256, 0, stream>>>(x, xb, M_ * C_);
  {
    dim3 g(N_QKV / 32, C_ / 32);
    transpose_bf16<<<g, 256, 0, stream>>>(W_attn, WaT, C_, N_QKV);
  }
  {
    dim3 g(C_ / 32, C_ / 32);
    transpose_bf16<<<g, 256, 0, stream>>>(W_proj, WpT, C_, C_);
  }
  gemm_qkv<<<(M_ / 128) * (N_QKV / 128), 256, 0, stream>>>(xb, WaT, b_attn, bQ, bK, qw, kw, vw);
  attn_kernel<<<ATTN_BLOCKS, 256, 0, stream>>>(qw, kw, vw, yw);
  gemm_proj<<<(M_ / 128) * (C_ / 128), 256, 0, stream>>>(yw, WpT, b_proj, out);
}

// Round 9
// 278.594 us; speedup vs baseline: 1.4226x; 1.0391x over previous
//
#include <hip/hip_runtime.h>

typedef unsigned short u16;
typedef unsigned int u32;
typedef unsigned long long u64;
typedef __bf16 bf16x8 __attribute__((ext_vector_type(8)));
typedef float f32x4 __attribute__((ext_vector_type(4)));

#define B_  4
#define T_  2048
#define C_  1024
#define NH_ 16
#define D_  64
#define M_  (B_*T_)          // 8192
#define N_QKV (3*C_)         // 3072

#define ATTN_BLOCKS 1024     // one (bh, tile-pair) per block, 4 blocks/CU

// raw barrier + static waitcnt (no vmcnt(0) drain -- keeps prefetch in flight)
#define BARRIER()  __asm__ __volatile__("s_barrier" ::: "memory")
#define WAIT_VM4() __asm__ __volatile__("s_waitcnt vmcnt(4)" ::: "memory")
#define WAIT_VM8() __asm__ __volatile__("s_waitcnt vmcnt(8)" ::: "memory")
#define WAIT_VM0() __asm__ __volatile__("s_waitcnt vmcnt(0)" ::: "memory")
#define LGKM0()    __asm__ __volatile__("s_waitcnt lgkmcnt(0)" ::: "memory")

// async global->LDS, 16B per lane. LDS dest = wave-uniform base + lane*16
__device__ __forceinline__ void async_copy16(void* lds, const void* gptr) {
  __builtin_amdgcn_global_load_lds(
      (const __attribute__((address_space(1))) u32*)gptr,
      (__attribute__((address_space(3))) u32*)(u32)(uintptr_t)lds,
      16, 0, 0);
}

// RNE float -> bf16 bits
__device__ __forceinline__ u16 f2bf(float f) {
  union { float f; unsigned u; } c; c.f = f;
  unsigned u = c.u;
  unsigned r = (u + 0x7fffu + ((u >> 16) & 1u)) >> 16;
  return (u16)r;
}

// ---------------- elementwise fp32 -> bf16 ----------------
__global__ __launch_bounds__(256) void conv_bf16(const float* __restrict__ in,
                                                 u16* __restrict__ out, int n) {
  int i = (blockIdx.x * 256 + threadIdx.x) * 4;
  if (i < n) {
    float4 f = *reinterpret_cast<const float4*>(in + i);
    u16 o[4] = { f2bf(f.x), f2bf(f.y), f2bf(f.z), f2bf(f.w) };
    *reinterpret_cast<uint2*>(out + i) = *reinterpret_cast<uint2*>(o);
  }
}

// ---------------- transpose fp32 [K][N] -> bf16 [N][K] ----------------
__global__ __launch_bounds__(256) void transpose_bf16(const float* __restrict__ in,
                                                      u16* __restrict__ out,
                                                      int K, int N) {
  __shared__ float tile[32][33];
  int bi = blockIdx.y;
  int bj = blockIdx.x;
  int tx = threadIdx.x & 31;
  int ty = threadIdx.x >> 5;
#pragma unroll
  for (int i = 0; i < 4; ++i) {
    int row = ty + i * 8;
    tile[row][tx] = in[(bi * 32 + row) * N + bj * 32 + tx];
  }
  __syncthreads();
#pragma unroll
  for (int i = 0; i < 4; ++i) {
    int row = ty + i * 8;
    out[(bj * 32 + row) * K + bi * 32 + tx] = f2bf(tile[tx][row]);
  }
}

// ---------------- QKV GEMM: 128x128, BK=64, prefetched 2-phase ----------------
// Q/K blocks (bn<16, uniform per block) compute the TRANSPOSED C fragment by
// swapping the MFMA operands -- lane holds 4 consecutive channels d in its
// r-quad -> one uint2 store; bias/bQ/bK become aligned float4 loads.
// (verified R6: qkv ~104 -> ~78 us)
__global__ __launch_bounds__(256, 2) void gemm_qkv(const u16* __restrict__ A,
                                                   const u16* __restrict__ Bt,
                                                   const float* __restrict__ b_attn,
                                                   const float* __restrict__ bQ,
                                                   const float* __restrict__ bK,
                                                   u16* __restrict__ qo,
                                                   u16* __restrict__ ko,
                                                   u16* __restrict__ vo) {
  const int K = C_;
  // bijective XCD swizzle: 1536 = 8 x 192; bm-major inside a chunk
  int bid = blockIdx.x;
  int wg = (bid & 7) * 192 + (bid >> 3);
  int bm = wg / 24, bn = wg % 24;
  const bool qk = (bn < 16);          // Q or K block (uniform)

  int tid = threadIdx.x;
  int wid = tid >> 6, lane = tid & 63;
  int lm = lane & 15, lq = lane >> 4;
  int wm = (wid >> 1) * 64, wn = (wid & 1) * 64;

  __shared__ u16 As[2][128 * 64];
  __shared__ u16 Bs[2][128 * 64];

  f32x4 acc[4][4];
#pragma unroll
  for (int i = 0; i < 4; ++i)
#pragma unroll
    for (int j = 0; j < 4; ++j) acc[i][j] = (f32x4){0.f, 0.f, 0.f, 0.f};

  const u16* Ab = A + (size_t)(bm * 128) * K;
  const u16* Bb = Bt + (size_t)(bn * 128) * K;
  int srow = lane >> 3;                  // row within 8-row chunk
  int sgc  = ((lane & 7) ^ srow) * 8;    // pre-swizzled global u16 col offset

  auto stage = [&](int bb, int t) {
#pragma unroll
    for (int i = 0; i < 4; ++i) {
      int c = i * 4 + wid;               // chunk 0..15 (8 rows, 1KB each)
      async_copy16(&As[bb][c * 512], Ab + (size_t)(c * 8 + srow) * K + t * 64 + sgc);
      async_copy16(&Bs[bb][c * 512], Bb + (size_t)(c * 8 + srow) * K + t * 64 + sgc);
    }
  };

  stage(0, 0);
  const int NT = K / 64;   // 16
  for (int t = 0; t < NT; ++t) {
    int bb = t & 1;
    int tn = (t + 1 < NT) ? t + 1 : t;   // clamp keeps vmcnt counts static
    stage(bb ^ 1, tn);                   // prefetch next tile
    WAIT_VM8();                          // this tile's 8 landed; next 8 flying
    BARRIER();
    bf16x8 af[4][2], bf[4][2];
#pragma unroll
    for (int mt = 0; mt < 4; ++mt) {
      const u16* base = &As[bb][(wm + mt * 16 + lm) * 64];
#pragma unroll
      for (int kh = 0; kh < 2; ++kh)
        af[mt][kh] = *reinterpret_cast<const bf16x8*>(base + (((kh * 4 + lq) ^ (lm & 7)) * 8));
    }
#pragma unroll
    for (int nt = 0; nt < 4; ++nt) {
      const u16* base = &Bs[bb][(wn + nt * 16 + lm) * 64];
#pragma unroll
      for (int kh = 0; kh < 2; ++kh)
        bf[nt][kh] = *reinterpret_cast<const bf16x8*>(base + (((kh * 4 + lq) ^ (lm & 7)) * 8));
    }
    if (qk) {
      // swapped operands: C' = C^T (row = n-dim, col = m-dim)
#pragma unroll
      for (int mt = 0; mt < 4; ++mt)
#pragma unroll
        for (int nt = 0; nt < 4; ++nt)
#pragma unroll
          for (int kh = 0; kh < 2; ++kh)
            acc[mt][nt] = __builtin_amdgcn_mfma_f32_16x16x32_bf16(bf[nt][kh], af[mt][kh],
                                                                  acc[mt][nt], 0, 0, 0);
    } else {
#pragma unroll
      for (int mt = 0; mt < 4; ++mt)
#pragma unroll
        for (int nt = 0; nt < 4; ++nt)
#pragma unroll
          for (int kh = 0; kh < 2; ++kh)
            acc[mt][nt] = __builtin_amdgcn_mfma_f32_16x16x32_bf16(af[mt][kh], bf[nt][kh],
                                                                  acc[mt][nt], 0, 0, 0);
    }
    LGKM0();                // this wave's reads of buf bb done...
    BARRIER();              // ...block-wide, before next iter overwrites it
  }
  WAIT_VM0();               // drain clamped tail prefetch before exit

  const float qscale = 0.18033688011112042f;  // 1/sqrt(64) * log2(e)
  if (qk) {
    // row = n (4 consecutive channels per lane), col = m (token)
    const float* bvec = (bn < 8) ? bQ : bK;
    u16* outp = (bn < 8) ? qo : ko;
    float scale = (bn < 8) ? qscale : 1.0f;
#pragma unroll
    for (int mt = 0; mt < 4; ++mt) {
#pragma unroll
      for (int nt = 0; nt < 4; ++nt) {
        int n0 = bn * 128 + wn + nt * 16 + lq * 4;
        int m  = bm * 128 + wm + mt * 16 + lm;
        int c0 = n0 & 1023;
        int h = c0 >> 6;
        int d0 = c0 & 63;
        int b = m >> 11;
        int tt = m & 2047;
        float4 ba = *reinterpret_cast<const float4*>(&b_attn[n0]);
        float4 bb = *reinterpret_cast<const float4*>(&bvec[c0]);
        u16 wb[4];
        wb[0] = f2bf((acc[mt][nt][0] + ba.x + bb.x) * scale);
        wb[1] = f2bf((acc[mt][nt][1] + ba.y + bb.y) * scale);
        wb[2] = f2bf((acc[mt][nt][2] + ba.z + bb.z) * scale);
        wb[3] = f2bf((acc[mt][nt][3] + ba.w + bb.w) * scale);
        *reinterpret_cast<uint2*>(&outp[((size_t)(b * NH_ + h) * T_ + tt) * D_ + d0]) =
            *reinterpret_cast<uint2*>(wb);
      }
    }
  } else {
    // V: row = m (4 consecutive tokens per lane), col = n -> uint2 into V^T
#pragma unroll
    for (int mt = 0; mt < 4; ++mt) {
#pragma unroll
      for (int nt = 0; nt < 4; ++nt) {
        int m0 = bm * 128 + wm + mt * 16 + lq * 4;
        int n = bn * 128 + wn + nt * 16 + lm;
        int c = n & 1023;
        int h = c >> 6;
        int d = c & 63;
        int b = m0 >> 11;
        int t0 = m0 & 2047;
        float bias = b_attn[n];
        u16 wb[4];
#pragma unroll
        for (int r = 0; r < 4; ++r) wb[r] = f2bf(acc[mt][nt][r] + bias);
        *reinterpret_cast<uint2*>(&vo[((size_t)(b * NH_ + h) * D_ + d) * T_ + t0]) =
            *reinterpret_cast<uint2*>(wb);
      }
    }
  }
}

// ---------------- Flash attention: paired 64-row tiles, uniform 33-iter blocks ----------------
// R8 post-mortem: one-item-per-block decays occupancy (avg 17 / max 32 iters
// -> 29.5% measured). This version: items are 64-row q-tiles (2048 of them,
// iters = tile+1); each block runs the complementary pair (j, 31-j) of the
// SAME bh back-to-back -> EVERY block = 33 iters + 2 prologues, balanced
// under any dispatch. Per-wave rows 32->16: the qt2 dimension disappears,
// halving live registers (no spill risk at the same launch bounds).
// Inner-loop body/softmax/LDS/barriers byte-identical to R8 per-iter.
// Item boundary: WAIT_VM0 drains own tail stages; iter-0's vmcnt(4)+barrier
// re-establishes the staging invariant (same proof as prologue).
// XCD affinity: bid&7 = XCD hosts bh {x, x+8..x+56} -> 8 bh x 512KB = 4MB L2.
__global__ __launch_bounds__(256, 4) void attn_kernel(const u16* __restrict__ q,
                                                      const u16* __restrict__ k,
                                                      const u16* __restrict__ vt,
                                                      u16* __restrict__ y) {
  int tid = threadIdx.x;
  int w = tid >> 6, lane = tid & 63;
  int lm = lane & 15, lq = lane >> 4;

  __shared__ u16 Ks[2][64 * 64];   // [buf][key][d swizzled]    16 KB
  __shared__ u16 Vs[2][64 * 64];   // [buf][d][key swizzled]    16 KB

  int srow = lane >> 3;            // staging row within 8-row chunk
  int sg   = (lane & 7) ^ srow;    // swizzled 16B col-group

  int bid = blockIdx.x;
  int x = bid & 7, g = bid >> 3;
  int bh = x + 8 * (g & 7);
  int jt = g >> 3;                 // 0..15 -> pair (jt, 31-jt)
  int b = bh >> 4, h = bh & 15;

  const u16* kb = k + (size_t)bh * T_ * D_;
  const u16* vb = vt + (size_t)bh * D_ * T_;   // [d][t]

  auto stage_K = [&](int buf, int kbi) {
    const u16* gb = kb + (size_t)(kbi * 64) * 64;
#pragma unroll
    for (int j = 0; j < 2; ++j) {
      int c = w * 2 + j;
      async_copy16(&Ks[buf][c * 512], gb + (c * 8 + srow) * 64 + sg * 8);
    }
  };
  auto stage_V = [&](int buf, int kbi) {
    const u16* gb = vb + kbi * 64;
#pragma unroll
    for (int j = 0; j < 2; ++j) {
      int c = w * 2 + j;
      async_copy16(&Vs[buf][c * 512], gb + (size_t)(c * 8 + srow) * T_ + sg * 8);
    }
  };

  for (int item = 0; item < 2; ++item) {
    const int tile = item ? (31 - jt) : jt;
    const int klast = tile;
    const int qrow0 = tile * 64 + w * 16;
    const u16* qb = q + ((size_t)bh * T_ + qrow0) * D_;

    // Q as B-operand: lane n=q=lm, k=d (pre-scaled by 1/sqrt(D)*log2e)
    bf16x8 bq[2];
    {
      const u16* qp = qb + lm * D_ + lq * 8;
      bq[0] = *reinterpret_cast<const bf16x8*>(qp);
      bq[1] = *reinterpret_cast<const bf16x8*>(qp + 32);
    }

    f32x4 o[4];
#pragma unroll
    for (int dt = 0; dt < 4; ++dt) o[dt] = (f32x4){0.f, 0.f, 0.f, 0.f};
    float mprev = -1e30f, lsum = 0.f;

    int t1 = (klast >= 1) ? 1 : 0;   // clamp keeps prologue vmcnt static
    stage_K(0, 0); stage_V(0, 0);
    stage_K(1, t1); stage_V(1, t1);

    for (int kbi = 0; kbi <= klast; ++kbi) {
      int buf = kbi & 1;
      WAIT_VM4();                // own share of tile kbi landed (kbi+1 flying)
      BARRIER();                 // all waves' shares landed

      // K frags: row=key=kt*16+lm, swizzled col-group
      bf16x8 kf[4][2];
#pragma unroll
      for (int kt = 0; kt < 4; ++kt) {
        const u16* base = &Ks[buf][(kt * 16 + lm) * 64];
        kf[kt][0] = *reinterpret_cast<const bf16x8*>(base + ((lq ^ (lm & 7)) * 8));
        kf[kt][1] = *reinterpret_cast<const bf16x8*>(base + (((4 + lq) ^ (lm & 7)) * 8));
      }

      // S^T[key][q]: lane (q=lm, lq) element r of s[kt] -> key kt*16+lq*4+r
      f32x4 s[4];
#pragma unroll
      for (int kt = 0; kt < 4; ++kt) {
        f32x4 z = (f32x4){0.f, 0.f, 0.f, 0.f};
        z = __builtin_amdgcn_mfma_f32_16x16x32_bf16(kf[kt][0], bq[0], z, 0, 0, 0);
        z = __builtin_amdgcn_mfma_f32_16x16x32_bf16(kf[kt][1], bq[1], z, 0, 0, 0);
        s[kt] = z;
      }

      bool maskt = (kbi * 64 + 63 > qrow0);
      int qg = qrow0 + lm;
      if (maskt) {
#pragma unroll
        for (int kt = 0; kt < 4; ++kt)
#pragma unroll
          for (int r = 0; r < 4; ++r) {
            int key = kbi * 64 + kt * 16 + lq * 4 + r;
            if (key > qg) s[kt][r] = -1e30f;
          }
      }
      float mx[4];
#pragma unroll
      for (int kt = 0; kt < 4; ++kt)
        mx[kt] = fmaxf(fmaxf(s[kt][0], s[kt][1]), fmaxf(s[kt][2], s[kt][3]));
      float mval = fmaxf(fmaxf(mx[0], mx[1]), fmaxf(mx[2], mx[3]));
      mval = fmaxf(mval, __shfl_xor(mval, 16));
      mval = fmaxf(mval, __shfl_xor(mval, 32));
      float mold = mprev;
      float mnew = fmaxf(mold, mval);
      unsigned long long upd = __ballot(mval > mold);
      if (upd) {
        float alpha = __builtin_exp2f(mold - mnew);
        lsum *= alpha;
#pragma unroll
        for (int dt = 0; dt < 4; ++dt) o[dt] *= alpha;
        mprev = mnew;
      }
      float rs = 0.f;
      unsigned pw[8];
#pragma unroll
      for (int kt = 0; kt < 4; ++kt) {
        unsigned pu[4];
#pragma unroll
        for (int r = 0; r < 4; ++r) {
          float p = __builtin_exp2f(s[kt][r] - mnew);
          rs += p;
          union { float f; unsigned u; } cc; cc.f = p;
          pu[r] = cc.u;
        }
        pw[kt * 2]     = __builtin_amdgcn_perm(pu[1], pu[0], 0x07060302u);
        pw[kt * 2 + 1] = __builtin_amdgcn_perm(pu[3], pu[2], 0x07060302u);
      }
      rs += __shfl_xor(rs, 16);
      rs += __shfl_xor(rs, 32);
      lsum += rs;
      bf16x8 pb[2];
      {
        union { unsigned u[4]; bf16x8 v; } b0, b1;
#pragma unroll
        for (int t = 0; t < 4; ++t) { b0.u[t] = pw[t]; b1.u[t] = pw[4 + t]; }
        pb[0] = b0.v;   // keys kt=0,1: slot (lq,j) -> key (j>>2)*16 + lq*4 + (j&3)
        pb[1] = b1.v;   // keys kt=2,3
      }

      // PV with the SAME permuted k-slot->key map on the V (A) operand
      {
        int r7 = lm & 7;
        int h4 = (lq & 1) * 4;
        int g0 = lq >> 1;
#pragma unroll
        for (int dt = 0; dt < 4; ++dt) {
          const u16* vbase = &Vs[buf][(dt * 16 + lm) * 64];
          union { u64 qd[2]; bf16x8 v; } t0, t1;
          t0.qd[0] = *reinterpret_cast<const u64*>(vbase + ((g0 ^ r7) * 8) + h4);
          t0.qd[1] = *reinterpret_cast<const u64*>(vbase + (((g0 + 2) ^ r7) * 8) + h4);
          t1.qd[0] = *reinterpret_cast<const u64*>(vbase + (((g0 + 4) ^ r7) * 8) + h4);
          t1.qd[1] = *reinterpret_cast<const u64*>(vbase + (((g0 + 6) ^ r7) * 8) + h4);
          o[dt] = __builtin_amdgcn_mfma_f32_16x16x32_bf16(t0.v, pb[0], o[dt], 0, 0, 0);
          o[dt] = __builtin_amdgcn_mfma_f32_16x16x32_bf16(t1.v, pb[1], o[dt], 0, 0, 0);
        }
      }

      BARRIER();                 // all waves done reading buf before overwrite
      int nk = (kbi + 2 <= klast) ? kbi + 2 : klast;
      stage_K(buf, nk); stage_V(buf, nk);
    }

    WAIT_VM0();  // drain own tail prefetches before item switch / exit

    // write y[b][t=q][h][d]; O^T C-layout: col=q=lm, row=d=dt*16+lq*4+r
    {
      float inv = 1.f / lsum;
      int qg = qrow0 + lm;
#pragma unroll
      for (int dt = 0; dt < 4; ++dt) {
        u16 wb[4];
#pragma unroll
        for (int r = 0; r < 4; ++r) wb[r] = f2bf(o[dt][r] * inv);
        int d = dt * 16 + lq * 4;
        *reinterpret_cast<uint2*>(&y[((size_t)(b * T_ + qg) * NH_ + h) * D_ + d]) =
            *reinterpret_cast<uint2*>(wb);
      }
    }
  }
}

// ---------------- Proj GEMM: 128x128, BK=64, prefetched 2-phase ----------------
// Swapped-operand epilogue: lane holds 4 consecutive n in its r-quad ->
// float4 stores + float4 bias loads.
__global__ __launch_bounds__(256, 2) void gemm_proj(const u16* __restrict__ A,
                                                    const u16* __restrict__ Bt,
                                                    const float* __restrict__ b_proj,
                                                    float* __restrict__ out) {
  const int K = C_, N = C_;
  int bid = blockIdx.x;
  int wg = (bid & 7) * 64 + (bid >> 3);   // 512 = 8 x 64 bijective
  int bm = wg / 8, bn = wg % 8;

  int tid = threadIdx.x;
  int wid = tid >> 6, lane = tid & 63;
  int lm = lane & 15, lq = lane >> 4;
  int wm = (wid >> 1) * 64, wn = (wid & 1) * 64;

  __shared__ u16 As[2][128 * 64];
  __shared__ u16 Bs[2][128 * 64];

  f32x4 acc[4][4];
#pragma unroll
  for (int i = 0; i < 4; ++i)
#pragma unroll
    for (int j = 0; j < 4; ++j) acc[i][j] = (f32x4){0.f, 0.f, 0.f, 0.f};

  const u16* Ab = A + (size_t)(bm * 128) * K;
  const u16* Bb = Bt + (size_t)(bn * 128) * K;
  int srow = lane >> 3;
  int sgc  = ((lane & 7) ^ srow) * 8;

  auto stage = [&](int bb, int t) {
#pragma unroll
    for (int i = 0; i < 4; ++i) {
      int c = i * 4 + wid;
      async_copy16(&As[bb][c * 512], Ab + (size_t)(c * 8 + srow) * K + t * 64 + sgc);
      async_copy16(&Bs[bb][c * 512], Bb + (size_t)(c * 8 + srow) * K + t * 64 + sgc);
    }
  };

  stage(0, 0);
  const int NT = K / 64;   // 16
  for (int t = 0; t < NT; ++t) {
    int bb = t & 1;
    int tn = (t + 1 < NT) ? t + 1 : t;
    stage(bb ^ 1, tn);
    WAIT_VM8();
    BARRIER();
    bf16x8 af[4][2], bf[4][2];
#pragma unroll
    for (int mt = 0; mt < 4; ++mt) {
      const u16* base = &As[bb][(wm + mt * 16 + lm) * 64];
#pragma unroll
      for (int kh = 0; kh < 2; ++kh)
        af[mt][kh] = *reinterpret_cast<const bf16x8*>(base + (((kh * 4 + lq) ^ (lm & 7)) * 8));
    }
#pragma unroll
    for (int nt = 0; nt < 4; ++nt) {
      const u16* base = &Bs[bb][(wn + nt * 16 + lm) * 64];
#pragma unroll
      for (int kh = 0; kh < 2; ++kh)
        bf[nt][kh] = *reinterpret_cast<const bf16x8*>(base + (((kh * 4 + lq) ^ (lm & 7)) * 8));
    }
    // swapped operands: row = n-dim, col = m-dim
#pragma unroll
    for (int mt = 0; mt < 4; ++mt)
#pragma unroll
      for (int nt = 0; nt < 4; ++nt)
#pragma unroll
        for (int kh = 0; kh < 2; ++kh)
          acc[mt][nt] = __builtin_amdgcn_mfma_f32_16x16x32_bf16(bf[nt][kh], af[mt][kh],
                                                                acc[mt][nt], 0, 0, 0);
    LGKM0();
    BARRIER();
  }
  WAIT_VM0();

#pragma unroll
  for (int mt = 0; mt < 4; ++mt) {
#pragma unroll
    for (int nt = 0; nt < 4; ++nt) {
      int n0 = bn * 128 + wn + nt * 16 + lq * 4;
      int m  = bm * 128 + wm + mt * 16 + lm;
      float4 bp = *reinterpret_cast<const float4*>(&b_proj[n0]);
      float4 res;
      res.x = acc[mt][nt][0] + bp.x;
      res.y = acc[mt][nt][1] + bp.y;
      res.z = acc[mt][nt][2] + bp.z;
      res.w = acc[mt][nt][3] + bp.w;
      *reinterpret_cast<float4*>(&out[(size_t)m * N + n0]) = res;
    }
  }
}

extern "C" void kernel_launch(void* const* d_in, const int* in_sizes, int n_in,
                              void* d_out, int out_size, void* d_ws, size_t ws_size,
                              hipStream_t stream) {
  const float* x      = (const float*)d_in[0];
  const float* W_attn = (const float*)d_in[1];
  const float* b_attn = (const float*)d_in[2];
  const float* bQ     = (const float*)d_in[3];
  const float* bK     = (const float*)d_in[4];
  const float* W_proj = (const float*)d_in[5];
  const float* b_proj = (const float*)d_in[6];
  float* out = (float*)d_out;

  char* ws = (char*)d_ws;
  u16* xb  = (u16*)(ws);                              // [8192][1024]      16 MB
  u16* WaT = (u16*)(ws + 16777216);                   // [3072][1024]       6 MB
  u16* WpT = (u16*)(ws + 23068672);                   // [1024][1024]       2 MB
  u16* qw  = (u16*)(ws + 25165824);                   // [B,NH,T,D] scaled 16 MB
  u16* kw  = (u16*)(ws + 41943040);                   // [B,NH,T,D]        16 MB
  u16* vw  = (u16*)(ws + 58720256);                   // [B,NH,D,T] (V^T)  16 MB
  u16* yw  = (u16*)(ws + 75497472);                   // [8192][1024]      16 MB

  conv_bf16<<<M_ * C_ / (4 * 256), 256, 0, stream>>>(x, xb, M_ * C_);
  {
    dim3 g(N_QKV / 32, C_ / 32);
    transpose_bf16<<<g, 256, 0, stream>>>(W_attn, WaT, C_, N_QKV);
  }
  {
    dim3 g(C_ / 32, C_ / 32);
    transpose_bf16<<<g, 256, 0, stream>>>(W_proj, WpT, C_, C_);
  }
  gemm_qkv<<<(M_ / 128) * (N_QKV / 128), 256, 0, stream>>>(xb, WaT, b_attn, bQ, bK, qw, kw, vw);
  attn_kernel<<<ATTN_BLOCKS, 256, 0, stream>>>(qw, kw, vw, yw);
  gemm_proj<<<(M_ / 128) * (C_ / 128), 256, 0, stream>>>(yw, WpT, b_proj, out);
}